// Round 1
// baseline (4644.785 us; speedup 1.0000x reference)
//
#include <hip/hip_runtime.h>

// ---------------- workspace layout (floats) ----------------
constexpr size_t OFF_XN  = 0;                      // 512*1024
constexpr size_t OFF_PF  = 524288;                 // 32768*128
constexpr size_t OFF_W2A = OFF_PF  + 4194304;      // 128*128*3  transposed [(cc*3+k)*128+d]
constexpr size_t OFF_W1B = OFF_W2A + 49152;
constexpr size_t OFF_W2B = OFF_W1B + 49152;
constexpr size_t OFF_PW  = OFF_W2B + 49152;        // [(c*16+k)*128+d]
constexpr size_t OFF_UPW = OFF_PW  + 262144;       // [(j*128+e)*128+d]
constexpr size_t OFF_W1D = OFF_UPW + 262144;       // [(c*3+k)*64+o]
constexpr size_t OFF_EMT = OFF_W1D + 24576;        // [j*128+d]
constexpr size_t OFF_EN  = OFF_EMT + 131072;       // 1024
constexpr size_t OFF_RP  = OFF_EN  + 1024;         // 4096 recon partials
constexpr size_t OFF_VP  = OFF_RP  + 4096;         // 4096 vq partials
constexpr size_t OFF_IND = OFF_VP  + 4096;         // 32768 int
constexpr size_t OFF_AP  = OFF_IND + 32768;        // 8192*2048 A-panel (per n-chunk)
// total = 22,365,184 floats = 89.5 MB

#define DI __device__ __forceinline__

// ---------------- prep: weight transposes + embedT + |e|^2 ----------------
__global__ __launch_bounds__(256) void k_prep(
    const float* __restrict__ w2a, const float* __restrict__ w1b, const float* __restrict__ w2b,
    const float* __restrict__ pw,  const float* __restrict__ upw, const float* __restrict__ w1d,
    const float* __restrict__ em,  float* __restrict__ ws)
{
  int tid = blockIdx.x * 256 + threadIdx.x;
  int stride = gridDim.x * 256;
  for (int i = tid; i < 128*128*3; i += stride) {
    int d = i / 384, r = i % 384;          // r = cc*3+k
    ws[OFF_W2A + (size_t)r*128 + d] = w2a[i];
    ws[OFF_W1B + (size_t)r*128 + d] = w1b[i];
    ws[OFF_W2B + (size_t)r*128 + d] = w2b[i];
  }
  for (int i = tid; i < 128*128*16; i += stride) {
    int d = i / 2048, r = i % 2048;        // r = c*16+k
    ws[OFF_PW + (size_t)r*128 + d] = pw[i];
  }
  for (int i = tid; i < 128*128*16; i += stride) {
    int e = i / 2048, rem = i % 2048;
    int d = rem / 16, j = rem % 16;
    ws[OFF_UPW + (size_t)(j*128 + e)*128 + d] = upw[i];
  }
  for (int i = tid; i < 64*128*3; i += stride) {
    int o = i / 384, r = i % 384;          // r = c*3+k
    ws[OFF_W1D + (size_t)r*64 + o] = w1d[i];
  }
  for (int j = tid; j < 1024; j += stride) {
    float s = 0.f;
    for (int d = 0; d < 128; ++d) {
      float v = em[d*1024 + j];
      ws[OFF_EMT + (size_t)j*128 + d] = v;
      s = fmaf(v, v, s);
    }
    ws[OFF_EN + j] = s;
  }
}

// ---------------- RevIN ----------------
__global__ __launch_bounds__(256) void k_revin(
    const float* __restrict__ x, const float* __restrict__ rw, const float* __restrict__ rb,
    float* __restrict__ xn)
{
  int n = blockIdx.x;            // sample = b*8 + c
  int b = n >> 3, c = n & 7;
  int t = threadIdx.x;
  const float* xp = x + (size_t)b*8192 + c;
  float v[4]; float s = 0.f, s2 = 0.f;
  #pragma unroll
  for (int i = 0; i < 4; ++i) {
    v[i] = xp[(size_t)(t + i*256)*8];
    s += v[i]; s2 = fmaf(v[i], v[i], s2);
  }
  __shared__ float sh[8];
  __shared__ float st[2];
  for (int o = 32; o; o >>= 1) { s += __shfl_down(s, o, 64); s2 += __shfl_down(s2, o, 64); }
  if ((t & 63) == 0) { sh[t >> 6] = s; sh[4 + (t >> 6)] = s2; }
  __syncthreads();
  if (t == 0) {
    float S = sh[0]+sh[1]+sh[2]+sh[3];
    float S2 = sh[4]+sh[5]+sh[6]+sh[7];
    float mu = S * (1.f/1024.f);
    float var = S2 * (1.f/1024.f) - mu*mu;
    st[0] = mu;
    st[1] = 1.f / sqrtf(var + 1e-5f);
  }
  __syncthreads();
  float mu = st[0], inv = st[1], w0 = rw[0], b0 = rb[0];
  #pragma unroll
  for (int i = 0; i < 4; ++i)
    xn[(size_t)n*1024 + t + i*256] = fmaf((v[i]-mu)*inv, w0, b0);
}

// ---------------- encoder conv core: 2 d's, NI cols, cc-range of 64 ----------------
template<int NI, int SRCW>
DI void conv_acc2(const float* __restrict__ wT, int d0, const float* src,
                  int ccb, int colb, float* a0, float* a1)
{
  for (int cc = ccb; cc < ccb + 64; ++cc) {
    const float* row = src + cc*SRCW + colb;
    float r[NI+2];
    #pragma unroll
    for (int x = 0; x < NI+2; x += 2) {
      float2 v = *(const float2*)(row + x);
      r[x] = v.x; r[x+1] = v.y;
    }
    const float* wp = wT + (size_t)cc*384 + d0;
    float2 w0 = *(const float2*)(wp);
    float2 w1 = *(const float2*)(wp + 128);
    float2 w2 = *(const float2*)(wp + 256);
    #pragma unroll
    for (int i = 0; i < NI; ++i) {
      a0[i] = fmaf(w0.x, r[i], fmaf(w1.x, r[i+1], fmaf(w2.x, r[i+2], a0[i])));
      a1[i] = fmaf(w0.y, r[i], fmaf(w1.y, r[i+1], fmaf(w2.y, r[i+2], a1[i])));
    }
  }
}

// ---------------- fused TCN encoder (block0 + block1) -> im2col A panel ----------------
// block = (nloc [0..127], ltile [0..31]); tile covers l in [l0, l0+32)
__global__ __launch_bounds__(256) void k_encoder(
    float* ws,
    const float* __restrict__ w1a, const float* __restrict__ b1a,
    const float* __restrict__ b2a, const float* __restrict__ wdw, const float* __restrict__ bdw,
    const float* __restrict__ b1b, const float* __restrict__ b2b,
    int n0)
{
  __shared__ __align__(16) float xs[40];
  __shared__ __align__(16) float h1a[128*40];   // l0-6 .. l0+31 (38 used)
  __shared__ __align__(16) float s0 [128*36];   // out0: l0-4 .. l0+31
  __shared__ __align__(16) float h1b[128*36];   // l0-2 .. l0+31 (34 used)
  __shared__ __align__(16) float scr[128*36];   // partial-sum scratch

  const float* xn   = ws + OFF_XN;
  const float* w2aT = ws + OFF_W2A;
  const float* w1bT = ws + OFF_W1B;
  const float* w2bT = ws + OFF_W2B;
  float* Apan = ws + OFF_AP;

  int blk = blockIdx.x;
  int nloc = blk >> 5;
  int n = n0 + nloc;
  int l0 = (blk & 31) * 32;
  int t = threadIdx.x;

  if (t < 40) {
    int gl = l0 - 8 + t;
    xs[t] = (gl >= 0 && gl < 1024) ? xn[(size_t)n*1024 + gl] : 0.f;
  }
  __syncthreads();

  // phase 1: h1a[c][i], l = l0-6+i, i in [0,38)
  {
    int c = t & 127, seg = t >> 7;
    float w0 = w1a[c*3+0], w1 = w1a[c*3+1], w2 = w1a[c*3+2], bb = b1a[c];
    #pragma unroll
    for (int ii = 0; ii < 19; ++ii) {
      int i = seg*19 + ii;
      float v = fmaf(w0, xs[i], fmaf(w1, xs[i+1], fmaf(w2, xs[i+2], bb)));
      // causal pad: positions l<0 must be ZERO (conv input pad), not relu(bias)
      h1a[c*40 + i] = (l0 - 6 + i >= 0) ? fmaxf(v, 0.f) : 0.f;
    }
  }
  __syncthreads();

  int dp = t & 63, d0 = dp*2;
  int sub = t >> 6;
  int hh = sub & 1;      // cc-half
  int g  = sub >> 1;     // col-half
  float a0[18], a1[18];

  // phase 2: out0 (36 cols, l = l0-4+col). h2 = relu(conv(h1a)+b2a); out0 = relu(h2 + wd*x + bd)
  {
    const int colb = g*18;
    float bi0 = hh ? 0.f : b2a[d0];
    float bi1 = hh ? 0.f : b2a[d0+1];
    #pragma unroll
    for (int i = 0; i < 18; ++i) { a0[i] = bi0; a1[i] = bi1; }
    conv_acc2<18,40>(w2aT, d0, h1a, hh*64, colb, a0, a1);
    if (hh) {
      #pragma unroll
      for (int i = 0; i < 18; ++i) { scr[d0*36 + colb+i] = a0[i]; scr[(d0+1)*36 + colb+i] = a1[i]; }
    }
    __syncthreads();
    if (!hh) {
      float wv0 = wdw[d0], wv1 = wdw[d0+1], c0 = bdw[d0], c1 = bdw[d0+1];
      #pragma unroll
      for (int i = 0; i < 18; ++i) {
        int col = colb + i;
        bool valid = (l0 - 4 + col >= 0);
        float h2a = fmaxf(a0[i] + scr[d0*36 + col], 0.f);
        float h2b = fmaxf(a1[i] + scr[(d0+1)*36 + col], 0.f);
        float xv = xs[col + 4];
        float o0 = fmaxf(h2a + fmaf(wv0, xv, c0), 0.f);
        float o1 = fmaxf(h2b + fmaf(wv1, xv, c1), 0.f);
        s0[d0*36 + col]     = valid ? o0 : 0.f;
        s0[(d0+1)*36 + col] = valid ? o1 : 0.f;
      }
    }
    __syncthreads();
  }

  // phase 3: h1b = relu(conv(s0)+b1b) (34 cols, l = l0-2+col)
  {
    const int colb = g*18;
    const int ni = g ? 16 : 18;
    float bi0 = hh ? 0.f : b1b[d0];
    float bi1 = hh ? 0.f : b1b[d0+1];
    #pragma unroll
    for (int i = 0; i < 18; ++i) { a0[i] = bi0; a1[i] = bi1; }
    if (!g) conv_acc2<18,36>(w1bT, d0, s0, hh*64, 0,  a0, a1);
    else    conv_acc2<16,36>(w1bT, d0, s0, hh*64, 18, a0, a1);
    if (hh) {
      #pragma unroll
      for (int i = 0; i < 18; ++i) {
        if (i < ni) { scr[d0*36 + colb+i] = a0[i]; scr[(d0+1)*36 + colb+i] = a1[i]; }
      }
    }
    __syncthreads();
    if (!hh) {
      #pragma unroll
      for (int i = 0; i < 18; ++i) {
        if (i < ni) {
          int col = colb + i;
          bool valid = (l0 - 2 + col >= 0);
          float v0 = fmaxf(a0[i] + scr[d0*36 + col], 0.f);
          float v1 = fmaxf(a1[i] + scr[(d0+1)*36 + col], 0.f);
          h1b[d0*36 + col]     = valid ? v0 : 0.f;
          h1b[(d0+1)*36 + col] = valid ? v1 : 0.f;
        }
      }
    }
    __syncthreads();
  }

  // phase 4: out1 = relu(relu(conv(h1b)+b2b) + out0) -> A panel [row=(nloc*64+p)][col=(c*16+k)]
  {
    const int colb = g*16;
    float bi0 = hh ? 0.f : b2b[d0];
    float bi1 = hh ? 0.f : b2b[d0+1];
    #pragma unroll
    for (int i = 0; i < 16; ++i) { a0[i] = bi0; a1[i] = bi1; }
    conv_acc2<16,36>(w2bT, d0, h1b, hh*64, colb, a0, a1);
    if (hh) {
      #pragma unroll
      for (int i = 0; i < 16; ++i) { scr[d0*36 + colb+i] = a0[i]; scr[(d0+1)*36 + colb+i] = a1[i]; }
    }
    __syncthreads();
    if (!hh) {
      #pragma unroll
      for (int i = 0; i < 16; ++i) {
        int col = colb + i;
        float h2a = fmaxf(a0[i] + scr[d0*36 + col], 0.f);
        float h2b = fmaxf(a1[i] + scr[(d0+1)*36 + col], 0.f);
        float v0 = fmaxf(h2a + s0[d0*36 + col + 4], 0.f);
        float v1 = fmaxf(h2b + s0[(d0+1)*36 + col + 4], 0.f);
        int l = l0 + col;
        int row = nloc*64 + (l >> 4);
        int k = l & 15;
        Apan[(size_t)row*2048 + d0*16 + k]     = v0;
        Apan[(size_t)row*2048 + (d0+1)*16 + k] = v1;
      }
    }
  }
}

// ---------------- patchify GEMM: pf[row][d] = A[row][:] @ pwT[:][d] + pb ----------------
__global__ __launch_bounds__(256) void k_patchify(float* ws, const float* __restrict__ pb, int chunk)
{
  __shared__ __align__(16) float As[32*68];
  __shared__ __align__(16) float Bs[64*128];
  const float* A  = ws + OFF_AP;
  const float* BT = ws + OFF_PW;
  float* pf = ws + OFF_PF;

  int t = threadIdx.x;
  int r0 = blockIdx.x * 32;
  int ty = t >> 4, tx = t & 15;   // ty: 2 rows each, tx: 8 cols each
  float acc[2][8] = {};

  for (int kc = 0; kc < 2048; kc += 64) {
    for (int q = t; q < 512; q += 256) {
      int row = q >> 4, k4 = q & 15;
      float4 v = *(const float4*)(A + (size_t)(r0+row)*2048 + kc + k4*4);
      *(float4*)(As + row*68 + k4*4) = v;
    }
    {
      const float4* src = (const float4*)(BT + (size_t)kc*128);
      float4* dst = (float4*)Bs;
      for (int q = t; q < 2048; q += 256) dst[q] = src[q];
    }
    __syncthreads();
    #pragma unroll 4
    for (int kk = 0; kk < 64; ++kk) {
      float av0 = As[(2*ty)*68 + kk];
      float av1 = As[(2*ty+1)*68 + kk];
      const float* bp = Bs + kk*128 + tx*8;
      float4 b0 = *(const float4*)bp;
      float4 b1 = *(const float4*)(bp + 4);
      acc[0][0]=fmaf(av0,b0.x,acc[0][0]); acc[0][1]=fmaf(av0,b0.y,acc[0][1]);
      acc[0][2]=fmaf(av0,b0.z,acc[0][2]); acc[0][3]=fmaf(av0,b0.w,acc[0][3]);
      acc[0][4]=fmaf(av0,b1.x,acc[0][4]); acc[0][5]=fmaf(av0,b1.y,acc[0][5]);
      acc[0][6]=fmaf(av0,b1.z,acc[0][6]); acc[0][7]=fmaf(av0,b1.w,acc[0][7]);
      acc[1][0]=fmaf(av1,b0.x,acc[1][0]); acc[1][1]=fmaf(av1,b0.y,acc[1][1]);
      acc[1][2]=fmaf(av1,b0.z,acc[1][2]); acc[1][3]=fmaf(av1,b0.w,acc[1][3]);
      acc[1][4]=fmaf(av1,b1.x,acc[1][4]); acc[1][5]=fmaf(av1,b1.y,acc[1][5]);
      acc[1][6]=fmaf(av1,b1.z,acc[1][6]); acc[1][7]=fmaf(av1,b1.w,acc[1][7]);
    }
    __syncthreads();
  }
  #pragma unroll
  for (int u = 0; u < 2; ++u) {
    size_t grow = (size_t)chunk*8192 + r0 + 2*ty + u;
    #pragma unroll
    for (int j = 0; j < 8; ++j)
      pf[grow*128 + tx*8 + j] = acc[u][j] + pb[tx*8 + j];
  }
}

// ---------------- VQ argmin: dist' = |e|^2 - 2 f.e (|f|^2 is row-constant) ----------------
__global__ __launch_bounds__(256) void k_vq(float* ws)
{
  __shared__ __align__(16) float fT[128*132];   // fT[d][rr], 128 rows of pf transposed
  __shared__ __align__(16) float ech[64*128];   // ech[jj][d]
  __shared__ float ens[64];
  __shared__ float2 red[128*16];
  const float* pf  = ws + OFF_PF;
  const float* emT = ws + OFF_EMT;
  const float* en  = ws + OFF_EN;
  int* ind = (int*)(ws + OFF_IND);

  int t = threadIdx.x;
  int r0 = blockIdx.x * 128;
  for (int s = t; s < 16384; s += 256) {
    int rr = s >> 7, d = s & 127;
    fT[d*132 + rr] = pf[(size_t)(r0 + rr)*128 + d];
  }
  int rg = t & 15, jg = t >> 4;   // rows 8*rg.., codes 4*jg..
  float bv[8]; int bi[8];
  #pragma unroll
  for (int r = 0; r < 8; ++r) { bv[r] = 3.4e38f; bi[r] = 0; }

  for (int ch = 0; ch < 16; ++ch) {
    __syncthreads();
    {
      const float4* src = (const float4*)(emT + (size_t)ch*8192);
      float4* dst = (float4*)ech;
      for (int q = t; q < 2048; q += 256) dst[q] = src[q];
      if (t < 64) ens[t] = en[ch*64 + t];
    }
    __syncthreads();
    float acc[8][4] = {};
    for (int db = 0; db < 128; db += 4) {
      float4 e0 = *(const float4*)(ech + (jg*4+0)*128 + db);
      float4 e1 = *(const float4*)(ech + (jg*4+1)*128 + db);
      float4 e2 = *(const float4*)(ech + (jg*4+2)*128 + db);
      float4 e3 = *(const float4*)(ech + (jg*4+3)*128 + db);
      #pragma unroll
      for (int u = 0; u < 4; ++u) {
        const float* fp = fT + (db+u)*132 + rg*8;
        float4 fa = *(const float4*)fp;
        float4 fb = *(const float4*)(fp + 4);
        float fv[8] = {fa.x,fa.y,fa.z,fa.w,fb.x,fb.y,fb.z,fb.w};
        float ev[4] = { ((const float*)&e0)[u], ((const float*)&e1)[u],
                        ((const float*)&e2)[u], ((const float*)&e3)[u] };
        #pragma unroll
        for (int r = 0; r < 8; ++r)
          #pragma unroll
          for (int j = 0; j < 4; ++j)
            acc[r][j] = fmaf(fv[r], ev[j], acc[r][j]);
      }
    }
    #pragma unroll
    for (int r = 0; r < 8; ++r)
      #pragma unroll
      for (int j = 0; j < 4; ++j) {
        float dist = ens[jg*4 + j] - 2.f*acc[r][j];
        int code = ch*64 + jg*4 + j;
        if (dist < bv[r]) { bv[r] = dist; bi[r] = code; }  // strict <: first index wins
      }
  }
  __syncthreads();
  #pragma unroll
  for (int r = 0; r < 8; ++r)
    red[(rg*8 + r)*16 + jg] = make_float2(bv[r], __int_as_float(bi[r]));
  __syncthreads();
  if (t < 128) {
    float2 v0 = red[t*16 + 0];
    float best = v0.x; int besti = __float_as_int(v0.y);
    for (int j = 1; j < 16; ++j) {
      float2 v = red[t*16 + j];
      int vi = __float_as_int(v.y);
      if (v.x < best || (v.x == best && vi < besti)) { best = v.x; besti = vi; }
    }
    ind[r0 + t] = besti;
  }
}

// ---------------- gather: z_q -> d_out, vq-loss partials ----------------
__global__ __launch_bounds__(256) void k_gather(float* ws, float* __restrict__ dout)
{
  const float* pf  = ws + OFF_PF;
  const float* emT = ws + OFF_EMT;
  const int* ind = (const int*)(ws + OFF_IND);
  float* vq_part = ws + OFF_VP;

  int t = threadIdx.x;
  int d = t & 127;
  float s = 0.f;
  #pragma unroll
  for (int it = 0; it < 4; ++it) {
    int rr = (t >> 7) + it*2;
    size_t row = (size_t)blockIdx.x*8 + rr;
    int idx = ind[row];
    float q = emT[(size_t)idx*128 + d];
    float f = pf[row*128 + d];
    float qm = q - f;
    dout[row*128 + d] = f + qm;   // z_q = pf + (q - pf), same rounding as ref
    s = fmaf(qm, qm, s);
  }
  __shared__ float sh[4];
  for (int o = 32; o; o >>= 1) s += __shfl_down(s, o, 64);
  if ((t & 63) == 0) sh[t >> 6] = s;
  __syncthreads();
  if (t == 0) vq_part[blockIdx.x] = sh[0]+sh[1]+sh[2]+sh[3];
}

// ---------------- decoder: up-proj + conv/gelu + conv + recon partials ----------------
__global__ __launch_bounds__(256) void k_decoder(
    const float* __restrict__ zq, float* ws,
    const float* __restrict__ upb, const float* __restrict__ db1,
    const float* __restrict__ dw2, const float* __restrict__ db2)
{
  constexpr int UPS = 148;
  __shared__ __align__(16) float ztT[128*12];       // ztT[e][pi], 10 z rows transposed
  __shared__ __align__(16) float up_s[128*UPS];     // cols <-> l in [l0-2, l0+130)
  __shared__ __align__(16) float d1_s[64*132];      // cols <-> l in [l0-1, l0+129)
  __shared__ __align__(16) float wch[3072];
  __shared__ float rsh[4];

  const float* upwT = ws + OFF_UPW;
  const float* w1dT = ws + OFF_W1D;
  const float* xn   = ws + OFF_XN;
  float* recon_part = ws + OFF_RP;

  int blk = blockIdx.x;
  int n = blk >> 3, tile = blk & 7;
  int l0 = tile*128, p0 = tile*8;
  int t = threadIdx.x;

  for (int s = t; s < 1280; s += 256) {
    int e = s & 127, pi = s >> 7;
    int p = p0 - 1 + pi;
    float v = 0.f;
    if (p >= 0 && p < 64) v = zq[((size_t)n*64 + p)*128 + e];
    ztT[e*12 + pi] = v;
  }
  __syncthreads();

  // phase U: up[d][l] = sum_e z[p][e]*up_w[e][d][j] + up_b  (l = 16p+j)
  int d = t & 127, eh = t >> 7;
  float* scrU = d1_s;                 // alias: d1_s unused during phase U
  float ub = upb[d];
  for (int jb = 0; jb < 4; ++jb) {
    float acc[4][10] = {};
    for (int e = eh*64; e < eh*64 + 64; ++e) {
      float4 z0 = *(const float4*)(ztT + e*12);
      float4 z1 = *(const float4*)(ztT + e*12 + 4);
      float2 z2 = *(const float2*)(ztT + e*12 + 8);
      float zr[10] = {z0.x,z0.y,z0.z,z0.w,z1.x,z1.y,z1.z,z1.w,z2.x,z2.y};
      #pragma unroll
      for (int jj = 0; jj < 4; ++jj) {
        float w = upwT[((size_t)(jb*4+jj)*128 + e)*128 + d];
        #pragma unroll
        for (int pi = 0; pi < 10; ++pi) acc[jj][pi] = fmaf(zr[pi], w, acc[jj][pi]);
      }
    }
    if (eh) {
      #pragma unroll
      for (int jj = 0; jj < 4; ++jj)
        #pragma unroll
        for (int pi = 0; pi < 10; ++pi) scrU[d*40 + jj*10 + pi] = acc[jj][pi];
    }
    __syncthreads();
    if (!eh) {
      #pragma unroll
      for (int jj = 0; jj < 4; ++jj)
        #pragma unroll
        for (int pi = 0; pi < 10; ++pi) {
          int j = jb*4 + jj;
          int l = (p0 - 1 + pi)*16 + j;
          int col = l - l0 + 2;
          if (col >= 0 && col < 132) {
            float v = 0.f;
            if ((unsigned)l < 1024u) v = acc[jj][pi] + scrU[d*40 + jj*10 + pi] + ub;
            up_s[d*UPS + col] = v;   // pad cells exactly 0
          }
        }
    }
    __syncthreads();
  }

  // phase D1: d1[o][col] = gelu(conv3(up)+b1), pad cells = 0
  int o2 = t & 31, q = t >> 5;
  int oA = 2*o2, oB = 2*o2 + 1;
  float accA[18] = {}, accB[18] = {};
  for (int cb = 0; cb < 8; ++cb) {
    __syncthreads();
    for (int s = t; s < 3072; s += 256) wch[s] = w1dT[(size_t)cb*3072 + s];
    __syncthreads();
    for (int cl = 0; cl < 16; ++cl) {
      int c = cb*16 + cl;
      const float* row = up_s + c*UPS + q*18;
      float r[20];
      #pragma unroll
      for (int x = 0; x < 20; x += 2) { float2 v = *(const float2*)(row + x); r[x]=v.x; r[x+1]=v.y; }
      float2 w0 = *(const float2*)(wch + (cl*3+0)*64 + oA);
      float2 w1 = *(const float2*)(wch + (cl*3+1)*64 + oA);
      float2 w2 = *(const float2*)(wch + (cl*3+2)*64 + oA);
      #pragma unroll
      for (int i = 0; i < 18; ++i) {
        accA[i] = fmaf(w0.x, r[i], fmaf(w1.x, r[i+1], fmaf(w2.x, r[i+2], accA[i])));
        accB[i] = fmaf(w0.y, r[i], fmaf(w1.y, r[i+1], fmaf(w2.y, r[i+2], accB[i])));
      }
    }
  }
  __syncthreads();   // everyone done reading wch & up_s
  {
    float bA = db1[oA], bB = db1[oB];
    #pragma unroll
    for (int i = 0; i < 18; ++i) {
      int col = q*18 + i;
      if (col < 130) {
        int l = l0 - 1 + col;
        float vA = 0.f, vB = 0.f;
        if ((unsigned)l < 1024u) {
          float xA = accA[i] + bA;
          vA = 0.5f*xA*(1.f + erff(xA*0.70710678118654752f));
          float xB = accB[i] + bB;
          vB = 0.5f*xB*(1.f + erff(xB*0.70710678118654752f));
        }
        d1_s[oA*132 + col] = vA;
        d1_s[oB*132 + col] = vB;
      }
    }
  }
  if (t < 192) wch[t] = dw2[t];
  __syncthreads();

  // phase D2 + recon partial
  float part = 0.f;
  if (t < 128) {
    int l = l0 + t;
    float acc = db2[0];
    for (int c = 0; c < 64; ++c) {
      acc = fmaf(wch[c*3+0], d1_s[c*132 + t],
            fmaf(wch[c*3+1], d1_s[c*132 + t + 1],
            fmaf(wch[c*3+2], d1_s[c*132 + t + 2], acc)));
    }
    float diff = acc - xn[(size_t)n*1024 + l];
    part = diff*diff;
  }
  for (int o = 32; o; o >>= 1) part += __shfl_down(part, o, 64);
  if ((t & 63) == 0) rsh[t >> 6] = part;
  __syncthreads();
  if (t == 0) recon_part[blk] = rsh[0]+rsh[1]+rsh[2]+rsh[3];
}

// ---------------- finalize loss ----------------
__global__ __launch_bounds__(256) void k_finalize(const float* __restrict__ ws, float* __restrict__ dout)
{
  const float* rp = ws + OFF_RP;
  const float* vp = ws + OFF_VP;
  int t = threadIdx.x;
  float s1 = 0.f, s2 = 0.f;
  for (int i = t; i < 4096; i += 256) { s1 += rp[i]; s2 += vp[i]; }
  __shared__ float sh[8];
  for (int o = 32; o; o >>= 1) { s1 += __shfl_down(s1,o,64); s2 += __shfl_down(s2,o,64); }
  if ((t & 63) == 0) { sh[t >> 6] = s1; sh[4 + (t >> 6)] = s2; }
  __syncthreads();
  if (t == 0) {
    float R = sh[0]+sh[1]+sh[2]+sh[3];
    float V = sh[4]+sh[5]+sh[6]+sh[7];
    dout[4194304] = R * (1.f/524288.f) + 0.25f * (V * (1.f/4194304.f));
  }
}

// ---------------- host ----------------
extern "C" void kernel_launch(void* const* d_in, const int* in_sizes, int n_in,
                              void* d_out, int out_size, void* d_ws, size_t ws_size,
                              hipStream_t stream)
{
  const float* x    = (const float*)d_in[0];
  const float* rw   = (const float*)d_in[1];
  const float* rb   = (const float*)d_in[2];
  const float* w1a  = (const float*)d_in[3];
  const float* b1a  = (const float*)d_in[4];
  const float* w2a  = (const float*)d_in[5];
  const float* b2a  = (const float*)d_in[6];
  const float* wda  = (const float*)d_in[7];
  const float* bda  = (const float*)d_in[8];
  const float* w1b  = (const float*)d_in[9];
  const float* b1b  = (const float*)d_in[10];
  const float* w2b  = (const float*)d_in[11];
  const float* b2b  = (const float*)d_in[12];
  const float* pw   = (const float*)d_in[13];
  const float* pb   = (const float*)d_in[14];
  const float* em   = (const float*)d_in[15];
  const float* upw  = (const float*)d_in[16];
  const float* upb  = (const float*)d_in[17];
  const float* dw1  = (const float*)d_in[18];
  const float* db1  = (const float*)d_in[19];
  const float* dw2  = (const float*)d_in[20];
  const float* db2  = (const float*)d_in[21];
  float* ws = (float*)d_ws;
  float* out = (float*)d_out;

  k_prep<<<256, 256, 0, stream>>>(w2a, w1b, w2b, pw, upw, dw1, em, ws);
  k_revin<<<512, 256, 0, stream>>>(x, rw, rb, ws + OFF_XN);
  for (int chunk = 0; chunk < 4; ++chunk) {
    k_encoder<<<4096, 256, 0, stream>>>(ws, w1a, b1a, b2a, wda, bda, b1b, b2b, chunk*128);
    k_patchify<<<256, 256, 0, stream>>>(ws, pb, chunk);
  }
  k_vq<<<256, 256, 0, stream>>>(ws);
  k_gather<<<4096, 256, 0, stream>>>(ws, out);
  k_decoder<<<4096, 256, 0, stream>>>(out, ws, upb, db1, dw2, db2);
  k_finalize<<<1, 256, 0, stream>>>(ws, out);
}